// Round 4
// baseline (1319.707 us; speedup 1.0000x reference)
//
#include <hip/hip_runtime.h>
#include <hip/hip_fp16.h>
#include <math.h>

#define N_NODES 100000
#define D_DIM   64
#define N_EDGES 1600000
#define P_L 0.5f
#define P_H 0.5f

#define NPB   32                       // nodes per bucket (exact: 32*3125=100000)
#define NB    3125                     // number of buckets
#define TILE  8192                     // edges per partition tile
#define NT    ((N_EDGES + TILE - 1) / TILE)   // 196 tiles

typedef unsigned int uint;
typedef unsigned short ushort_t;

__device__ inline ushort_t f2bf(float f) {
    uint u = __float_as_uint(f);
    uint r = (u + 0x7fffu + ((u >> 16) & 1u)) >> 16;
    return (ushort_t)r;
}
__device__ inline float bf2f(uint u) { return __uint_as_float(u << 16); }

// fast tanh for x >= 0
__device__ inline float tanh_pos(float x) {
    return 1.f - 2.f / (__expf(2.f * x) + 1.f);
}

// ---------------------------------------------------------------------------
// K0: transpose Wr [64c][128k] -> wrt [128k][64c]
// ---------------------------------------------------------------------------
__global__ __launch_bounds__(256) void transpose_wr_kernel(const float* __restrict__ Wr,
                                                           float* __restrict__ wrt) {
    for (int idx = threadIdx.x; idx < 64 * 128; idx += 256) {
        int c = idx >> 7;
        int k = idx & 127;
        wrt[k * 64 + c] = Wr[idx];
    }
}

// ---------------------------------------------------------------------------
// K1: per-node gate projections + h -> bf16. One wave per node.
//   gdst4[n] = (h.Wl[:64], h.Wh[:64], d[n], 0)
//   gsrc4[n] = (h.Wl[64:], h.Wh[64:], d[n], 0)
// ---------------------------------------------------------------------------
__global__ __launch_bounds__(256) void node_gates_kernel(
    const float* __restrict__ h, const float* __restrict__ dvec,
    const float* __restrict__ Wl, const float* __restrict__ Wh,
    ushort_t* __restrict__ hbf,
    float4* __restrict__ gdst4, float4* __restrict__ gsrc4)
{
    int tid = threadIdx.x;
    int node = blockIdx.x * 4 + (tid >> 6);
    if (node >= N_NODES) return;
    int lane = tid & 63;

    float hv = h[(size_t)node * 64 + lane];
    hbf[(size_t)node * 64 + lane] = f2bf(hv);

    float pld = hv * Wl[lane];
    float pls = hv * Wl[64 + lane];
    float phd = hv * Wh[lane];
    float phs = hv * Wh[64 + lane];
    #pragma unroll
    for (int m = 32; m >= 1; m >>= 1) {
        pld += __shfl_xor(pld, m);
        pls += __shfl_xor(pls, m);
        phd += __shfl_xor(phd, m);
        phs += __shfl_xor(phs, m);
    }
    if (lane == 0) {
        float d = dvec[node];
        gdst4[node] = make_float4(pld, phd, d, 0.f);
        gsrc4[node] = make_float4(pls, phs, d, 0.f);
    }
}

// ---------------------------------------------------------------------------
// K2: per-tile bucket histogram (LDS atomics only) -> T[tile][bucket]
// ---------------------------------------------------------------------------
__global__ __launch_bounds__(1024) void bucket_hist_kernel(const int* __restrict__ dst,
                                                           int* __restrict__ T) {
    __shared__ int hist[NB];
    int tid = threadIdx.x;
    for (int i = tid; i < NB; i += 1024) hist[i] = 0;
    __syncthreads();
    int base = blockIdx.x * TILE;
    #pragma unroll
    for (int j = 0; j < TILE / 1024; ++j) {
        int e = base + j * 1024 + tid;
        if (e < N_EDGES) atomicAdd(&hist[dst[e] >> 5], 1);
    }
    __syncthreads();
    int* row = T + (size_t)blockIdx.x * NB;
    for (int i = tid; i < NB; i += 1024) row[i] = hist[i];
}

// ---------------------------------------------------------------------------
// K3a: column scan of T: T[w][b] becomes exclusive prefix over tiles;
//       totG[b] = column total. Grid covers NB threads.
// ---------------------------------------------------------------------------
__global__ __launch_bounds__(1024) void scanA_kernel(int* __restrict__ T,
                                                     int* __restrict__ totG) {
    int b = blockIdx.x * 1024 + threadIdx.x;
    if (b >= NB) return;
    int run = 0;
    for (int w = 0; w < NT; ++w) {
        int idx = w * NB + b;
        int v = T[idx];
        T[idx] = run;
        run += v;
    }
    totG[b] = run;
}

// ---------------------------------------------------------------------------
// K3b: exclusive scan of totG[NB] -> baseG[NB], bucketoffs[NB+1]. One block.
// ---------------------------------------------------------------------------
__global__ __launch_bounds__(1024) void scanB_kernel(const int* __restrict__ totG,
                                                     int* __restrict__ baseG,
                                                     int* __restrict__ bucketoffs) {
    __shared__ int scan_lds[1024];
    int tid = threadIdx.x;
    int a[4];
    int s = 0;
    #pragma unroll
    for (int i = 0; i < 4; ++i) {
        int b = tid * 4 + i;
        a[i] = (b < NB) ? totG[b] : 0;
        s += a[i];
    }
    scan_lds[tid] = s;
    __syncthreads();
    for (int d = 1; d < 1024; d <<= 1) {
        int v = (tid >= d) ? scan_lds[tid - d] : 0;
        __syncthreads();
        scan_lds[tid] += v;
        __syncthreads();
    }
    int excl = scan_lds[tid] - s;
    int total = scan_lds[1023];
    #pragma unroll
    for (int i = 0; i < 4; ++i) {
        int b = tid * 4 + i;
        if (b < NB) { baseG[b] = excl; bucketoffs[b] = excl; }
        excl += a[i];
    }
    if (tid == 0) bucketoffs[NB] = total;
}

// ---------------------------------------------------------------------------
// K4: place edges into bucket-partitioned ebuf. LDS cursors only (no global
// atomics). Record: (src | dstLocal<<17, half el | half eh << 16).
// ---------------------------------------------------------------------------
__global__ __launch_bounds__(1024) void place_kernel(
    const int* __restrict__ src, const int* __restrict__ dst,
    const int* __restrict__ T, const int* __restrict__ baseG,
    const float4* __restrict__ gdst4, const float4* __restrict__ gsrc4,
    const float* __restrict__ bl, const float* __restrict__ bh,
    uint2* __restrict__ ebuf)
{
    __shared__ int cur[NB];
    int tid = threadIdx.x;
    const int* row = T + (size_t)blockIdx.x * NB;
    for (int i = tid; i < NB; i += 1024) cur[i] = row[i] + baseG[i];
    __syncthreads();

    float bl0 = bl[0], bh0 = bh[0];
    int base = blockIdx.x * TILE;
    #pragma unroll
    for (int j = 0; j < TILE / 1024; ++j) {
        int e = base + j * 1024 + tid;
        if (e >= N_EDGES) continue;
        int t = dst[e];
        int s = src[e];
        float4 gt = gdst4[t];
        float4 gs = gsrc4[s];
        float xl = gt.x + gs.x + bl0;
        float xh = gt.y + gs.y + bh0;
        float ll = xl > 0.f ? xl : -P_L * xl;   // leaky, always >= 0
        float hh = xh > 0.f ? xh : -P_H * xh;
        float dd = gt.z * gs.z;
        float el =  tanh_pos(ll) * dd;
        float eh = -tanh_pos(hh) * dd;
        uint ge = (uint)__half_as_ushort(__float2half_rn(el))
                | ((uint)__half_as_ushort(__float2half_rn(eh)) << 16);
        int b  = t >> 5;
        uint dl = (uint)(t & 31);
        int pos = atomicAdd(&cur[b], 1);        // LDS atomic
        ebuf[pos] = make_uint2((uint)s | (dl << 17), ge);
    }
}

// ---------------------------------------------------------------------------
// K5: per-bucket accumulate (fp32 z in LDS, ds_add_f32) + fused Wr transform.
// One workgroup (256 thr = 4 waves) per bucket of 32 nodes.
// z layout: [32 nodes][129] (pad -> bank (dl+lane)%32: 2 lanes/bank = free)
// ---------------------------------------------------------------------------
__global__ __launch_bounds__(256) void accum_final_kernel(
    const int* __restrict__ bucketoffs, const uint2* __restrict__ ebuf,
    const ushort_t* __restrict__ hbf, const float* __restrict__ wrt,
    const float* __restrict__ br, float* __restrict__ out)
{
    __shared__ float z[NPB * 129];
    int tid = threadIdx.x;
    for (int i = tid; i < NPB * 129; i += 256) z[i] = 0.f;
    __syncthreads();

    int bk = blockIdx.x;
    int beg = bucketoffs[bk];
    int end = bucketoffs[bk + 1];
    int wave = tid >> 6;
    int lane = tid & 63;

    int k = beg + wave;
    // unrolled by 2 for load-latency overlap
    for (; k + 4 < end; k += 8) {
        uint2 r1 = ebuf[k];
        uint2 r2 = ebuf[k + 4];
        int s1 = r1.x & 0x1FFFF;
        int s2 = r2.x & 0x1FFFF;
        float hv1 = bf2f((uint)hbf[s1 * 64 + lane]);
        float hv2 = bf2f((uint)hbf[s2 * 64 + lane]);
        int dl1 = (r1.x >> 17) & 31;
        int dl2 = (r2.x >> 17) & 31;
        float el1 = __half2float(__ushort_as_half((unsigned short)(r1.y & 0xffffu)));
        float eh1 = __half2float(__ushort_as_half((unsigned short)(r1.y >> 16)));
        float el2 = __half2float(__ushort_as_half((unsigned short)(r2.y & 0xffffu)));
        float eh2 = __half2float(__ushort_as_half((unsigned short)(r2.y >> 16)));
        atomicAdd(&z[dl1 * 129 + lane],      el1 * hv1);
        atomicAdd(&z[dl1 * 129 + 64 + lane], eh1 * hv1);
        atomicAdd(&z[dl2 * 129 + lane],      el2 * hv2);
        atomicAdd(&z[dl2 * 129 + 64 + lane], eh2 * hv2);
    }
    if (k < end) {
        uint2 r1 = ebuf[k];
        int s1 = r1.x & 0x1FFFF;
        float hv1 = bf2f((uint)hbf[s1 * 64 + lane]);
        int dl1 = (r1.x >> 17) & 31;
        float el1 = __half2float(__ushort_as_half((unsigned short)(r1.y & 0xffffu)));
        float eh1 = __half2float(__ushort_as_half((unsigned short)(r1.y >> 16)));
        atomicAdd(&z[dl1 * 129 + lane],      el1 * hv1);
        atomicAdd(&z[dl1 * 129 + 64 + lane], eh1 * hv1);
    }
    __syncthreads();

    // fused final transform: out[n] = z[n] . wrt + br
    int node = tid >> 3;          // 0..31
    int g = tid & 7;              // 8-col group
    float acc[8];
    #pragma unroll
    for (int j = 0; j < 8; ++j) acc[j] = 0.f;
    const float* zrow = z + node * 129;
    #pragma unroll 4
    for (int kk = 0; kk < 128; ++kk) {
        float zv = zrow[kk];                      // bank (node+kk)%32, 8-lane bcast
        const float* w = wrt + kk * 64 + g * 8;
        float4 w0 = *(const float4*)(w);
        float4 w1 = *(const float4*)(w + 4);
        acc[0] += zv * w0.x; acc[1] += zv * w0.y; acc[2] += zv * w0.z; acc[3] += zv * w0.w;
        acc[4] += zv * w1.x; acc[5] += zv * w1.y; acc[6] += zv * w1.z; acc[7] += zv * w1.w;
    }
    int n = bk * NPB + node;
    float* op = out + (size_t)n * 64 + g * 8;
    const float* bp = br + g * 8;
    *(float4*)(op)     = make_float4(acc[0] + bp[0], acc[1] + bp[1], acc[2] + bp[2], acc[3] + bp[3]);
    *(float4*)(op + 4) = make_float4(acc[4] + bp[4], acc[5] + bp[5], acc[6] + bp[6], acc[7] + bp[7]);
}

// ---------------------------------------------------------------------------
extern "C" void kernel_launch(void* const* d_in, const int* in_sizes, int n_in,
                              void* d_out, int out_size, void* d_ws, size_t ws_size,
                              hipStream_t stream) {
    const float* h    = (const float*)d_in[0];
    const float* dvec = (const float*)d_in[1];
    const int*   src  = (const int*)  d_in[2];
    const int*   dst  = (const int*)  d_in[3];
    const float* Wl   = (const float*)d_in[4];
    const float* bl   = (const float*)d_in[5];
    const float* Wh   = (const float*)d_in[6];
    const float* bh   = (const float*)d_in[7];
    const float* Wr   = (const float*)d_in[8];
    const float* br   = (const float*)d_in[9];
    float* out = (float*)d_out;

    char* ws = (char*)d_ws;
    size_t off = 0;
    auto alloc = [&](size_t bytes) { char* p = ws + off; off += (bytes + 255) & ~size_t(255); return p; };

    ushort_t* hbf       = (ushort_t*)alloc((size_t)N_NODES * 64 * 2);     // 12.8 MB
    float4*   gdst4     = (float4*)  alloc((size_t)N_NODES * 16);         // 1.6 MB
    float4*   gsrc4     = (float4*)  alloc((size_t)N_NODES * 16);         // 1.6 MB
    float*    wrt       = (float*)   alloc(64 * 128 * 4);                 // 32 KB
    int*      T         = (int*)     alloc((size_t)NT * NB * 4);          // 2.45 MB
    int*      totG      = (int*)     alloc((size_t)NB * 4);
    int*      baseG     = (int*)     alloc((size_t)NB * 4);
    int*      bucketoffs= (int*)     alloc((size_t)(NB + 1) * 4);
    uint2*    ebuf      = (uint2*)   alloc((size_t)N_EDGES * 8);          // 12.8 MB

    transpose_wr_kernel<<<1, 256, 0, stream>>>(Wr, wrt);
    node_gates_kernel<<<(N_NODES + 3) / 4, 256, 0, stream>>>(h, dvec, Wl, Wh, hbf, gdst4, gsrc4);
    bucket_hist_kernel<<<NT, 1024, 0, stream>>>(dst, T);
    scanA_kernel<<<(NB + 1023) / 1024, 1024, 0, stream>>>(T, totG);
    scanB_kernel<<<1, 1024, 0, stream>>>(totG, baseG, bucketoffs);
    place_kernel<<<NT, 1024, 0, stream>>>(src, dst, T, baseG, gdst4, gsrc4, bl, bh, ebuf);
    accum_final_kernel<<<NB, 256, 0, stream>>>(bucketoffs, ebuf, hbf, wrt, br, out);
}

// Round 5
// 1300.935 us; speedup vs baseline: 1.0144x; 1.0144x over previous
//
#include <hip/hip_runtime.h>
#include <hip/hip_fp16.h>
#include <math.h>

#define N_NODES 100000
#define D_DIM   64
#define N_EDGES 1600000
#define P_L 0.5f
#define P_H 0.5f

#define NPB   32                       // nodes per bucket (exact: 32*3125=100000)
#define NB    3125                     // number of buckets
#define TILE  8192                     // edges per partition tile
#define NT    ((N_EDGES + TILE - 1) / TILE)   // 196 tiles

typedef unsigned int uint;
typedef unsigned short ushort_t;

__device__ inline ushort_t f2bf(float f) {
    uint u = __float_as_uint(f);
    uint r = (u + 0x7fffu + ((u >> 16) & 1u)) >> 16;
    return (ushort_t)r;
}
__device__ inline float bf2f(uint u) { return __uint_as_float(u << 16); }

// fast tanh for x >= 0
__device__ inline float tanh_pos(float x) {
    return 1.f - 2.f / (__expf(2.f * x) + 1.f);
}

// ---------------------------------------------------------------------------
// K0: transpose Wr [64c][128k] -> wrt [128k][64c]
// ---------------------------------------------------------------------------
__global__ __launch_bounds__(256) void transpose_wr_kernel(const float* __restrict__ Wr,
                                                           float* __restrict__ wrt) {
    for (int idx = threadIdx.x; idx < 64 * 128; idx += 256) {
        int c = idx >> 7;
        int k = idx & 127;
        wrt[k * 64 + c] = Wr[idx];
    }
}

// ---------------------------------------------------------------------------
// K1: per-node gate projections + h -> bf16. One wave per node.
//   gdst4[n] = (h.Wl[:64], h.Wh[:64], d[n], 0)
//   gsrc4[n] = (h.Wl[64:], h.Wh[64:], d[n], 0)
// ---------------------------------------------------------------------------
__global__ __launch_bounds__(256) void node_gates_kernel(
    const float* __restrict__ h, const float* __restrict__ dvec,
    const float* __restrict__ Wl, const float* __restrict__ Wh,
    ushort_t* __restrict__ hbf,
    float4* __restrict__ gdst4, float4* __restrict__ gsrc4)
{
    int tid = threadIdx.x;
    int node = blockIdx.x * 4 + (tid >> 6);
    if (node >= N_NODES) return;
    int lane = tid & 63;

    float hv = h[(size_t)node * 64 + lane];
    hbf[(size_t)node * 64 + lane] = f2bf(hv);

    float pld = hv * Wl[lane];
    float pls = hv * Wl[64 + lane];
    float phd = hv * Wh[lane];
    float phs = hv * Wh[64 + lane];
    #pragma unroll
    for (int m = 32; m >= 1; m >>= 1) {
        pld += __shfl_xor(pld, m);
        pls += __shfl_xor(pls, m);
        phd += __shfl_xor(phd, m);
        phs += __shfl_xor(phs, m);
    }
    if (lane == 0) {
        float d = dvec[node];
        gdst4[node] = make_float4(pld, phd, d, 0.f);
        gsrc4[node] = make_float4(pls, phs, d, 0.f);
    }
}

// ---------------------------------------------------------------------------
// K2: per-tile bucket histogram (LDS atomics only) -> T[tile][bucket]
// ---------------------------------------------------------------------------
__global__ __launch_bounds__(1024) void bucket_hist_kernel(const int* __restrict__ dst,
                                                           int* __restrict__ T) {
    __shared__ int hist[NB];
    int tid = threadIdx.x;
    for (int i = tid; i < NB; i += 1024) hist[i] = 0;
    __syncthreads();
    int base = blockIdx.x * TILE;
    #pragma unroll
    for (int j = 0; j < TILE / 1024; ++j) {
        int e = base + j * 1024 + tid;
        if (e < N_EDGES) atomicAdd(&hist[dst[e] >> 5], 1);
    }
    __syncthreads();
    int* row = T + (size_t)blockIdx.x * NB;
    for (int i = tid; i < NB; i += 1024) row[i] = hist[i];
}

// ---------------------------------------------------------------------------
// K3a: column scan of T: T[w][b] becomes exclusive prefix over tiles;
//       totG[b] = column total.
// ---------------------------------------------------------------------------
__global__ __launch_bounds__(1024) void scanA_kernel(int* __restrict__ T,
                                                     int* __restrict__ totG) {
    int b = blockIdx.x * 1024 + threadIdx.x;
    if (b >= NB) return;
    int run = 0;
    for (int w = 0; w < NT; ++w) {
        int idx = w * NB + b;
        int v = T[idx];
        T[idx] = run;
        run += v;
    }
    totG[b] = run;
}

// ---------------------------------------------------------------------------
// K3b: exclusive scan of totG[NB] -> baseG[NB], bucketoffs[NB+1]. One block.
// ---------------------------------------------------------------------------
__global__ __launch_bounds__(1024) void scanB_kernel(const int* __restrict__ totG,
                                                     int* __restrict__ baseG,
                                                     int* __restrict__ bucketoffs) {
    __shared__ int scan_lds[1024];
    int tid = threadIdx.x;
    int a[4];
    int s = 0;
    #pragma unroll
    for (int i = 0; i < 4; ++i) {
        int b = tid * 4 + i;
        a[i] = (b < NB) ? totG[b] : 0;
        s += a[i];
    }
    scan_lds[tid] = s;
    __syncthreads();
    for (int d = 1; d < 1024; d <<= 1) {
        int v = (tid >= d) ? scan_lds[tid - d] : 0;
        __syncthreads();
        scan_lds[tid] += v;
        __syncthreads();
    }
    int excl = scan_lds[tid] - s;
    int total = scan_lds[1023];
    #pragma unroll
    for (int i = 0; i < 4; ++i) {
        int b = tid * 4 + i;
        if (b < NB) { baseG[b] = excl; bucketoffs[b] = excl; }
        excl += a[i];
    }
    if (tid == 0) bucketoffs[NB] = total;
}

// ---------------------------------------------------------------------------
// K4: place edges into bucket-partitioned ebuf. LDS cursors only (no global
// atomics). Record: (src | dstLocal<<17, half el | half eh << 16).
// ---------------------------------------------------------------------------
__global__ __launch_bounds__(1024) void place_kernel(
    const int* __restrict__ src, const int* __restrict__ dst,
    const int* __restrict__ T, const int* __restrict__ baseG,
    const float4* __restrict__ gdst4, const float4* __restrict__ gsrc4,
    const float* __restrict__ bl, const float* __restrict__ bh,
    uint2* __restrict__ ebuf)
{
    __shared__ int cur[NB];
    int tid = threadIdx.x;
    const int* row = T + (size_t)blockIdx.x * NB;
    for (int i = tid; i < NB; i += 1024) cur[i] = row[i] + baseG[i];
    __syncthreads();

    float bl0 = bl[0], bh0 = bh[0];
    int base = blockIdx.x * TILE;
    #pragma unroll
    for (int j = 0; j < TILE / 1024; ++j) {
        int e = base + j * 1024 + tid;
        if (e >= N_EDGES) continue;
        int t = dst[e];
        int s = src[e];
        float4 gt = gdst4[t];
        float4 gs = gsrc4[s];
        float xl = gt.x + gs.x + bl0;
        float xh = gt.y + gs.y + bh0;
        float ll = xl > 0.f ? xl : -P_L * xl;   // leaky, always >= 0
        float hh = xh > 0.f ? xh : -P_H * xh;
        float dd = gt.z * gs.z;
        float el =  tanh_pos(ll) * dd;
        float eh = -tanh_pos(hh) * dd;
        uint ge = (uint)__half_as_ushort(__float2half_rn(el))
                | ((uint)__half_as_ushort(__float2half_rn(eh)) << 16);
        int b  = t >> 5;
        uint dl = (uint)(t & 31);
        int pos = atomicAdd(&cur[b], 1);        // LDS atomic
        ebuf[pos] = make_uint2((uint)s | (dl << 17), ge);
    }
}

// ---------------------------------------------------------------------------
// K5: per-bucket accumulate + fused Wr transform.
// 256 thr = 16 subgroups of 16 lanes. Each subgroup takes one record per
// iteration (x2 unroll -> 32 independent gather chains per block). Lane owns
// a 4-dim slice: 8 B bf16 hbf load, 8 ds_add_f32 into padded z[32][129].
// ---------------------------------------------------------------------------
__global__ __launch_bounds__(256) void accum_final_kernel(
    const int* __restrict__ bucketoffs, const uint2* __restrict__ ebuf,
    const ushort_t* __restrict__ hbf, const float* __restrict__ wrt,
    const float* __restrict__ br, float* __restrict__ out)
{
    __shared__ float z[NPB * 129];
    int tid = threadIdx.x;
    for (int i = tid; i < NPB * 129; i += 256) z[i] = 0.f;
    __syncthreads();

    int bk = blockIdx.x;
    int beg = bucketoffs[bk];
    int end = bucketoffs[bk + 1];
    int sub = tid >> 4;          // 0..15 subgroup id
    int l16 = tid & 15;          // 4-dim slice index

    int k = beg + sub;
    for (; k + 16 < end; k += 32) {
        uint2 r1 = ebuf[k];          // per-subgroup address -> VMEM, L1 bcast
        uint2 r2 = ebuf[k + 16];
        int s1 = r1.x & 0x1FFFF;
        int s2 = r2.x & 0x1FFFF;
        uint2 hv1 = *(const uint2*)(hbf + (size_t)s1 * 64 + l16 * 4);
        uint2 hv2 = *(const uint2*)(hbf + (size_t)s2 * 64 + l16 * 4);

        int dl1 = (r1.x >> 17) & 31;
        float el1 = __half2float(__ushort_as_half((unsigned short)(r1.y & 0xffffu)));
        float eh1 = __half2float(__ushort_as_half((unsigned short)(r1.y >> 16)));
        float a0 = bf2f(hv1.x & 0xffffu), a1 = bf2f(hv1.x >> 16);
        float a2 = bf2f(hv1.y & 0xffffu), a3 = bf2f(hv1.y >> 16);
        float* zl1 = &z[dl1 * 129 + l16 * 4];
        atomicAdd(zl1 + 0,  el1 * a0);
        atomicAdd(zl1 + 1,  el1 * a1);
        atomicAdd(zl1 + 2,  el1 * a2);
        atomicAdd(zl1 + 3,  el1 * a3);
        atomicAdd(zl1 + 64, eh1 * a0);
        atomicAdd(zl1 + 65, eh1 * a1);
        atomicAdd(zl1 + 66, eh1 * a2);
        atomicAdd(zl1 + 67, eh1 * a3);

        int dl2 = (r2.x >> 17) & 31;
        float el2 = __half2float(__ushort_as_half((unsigned short)(r2.y & 0xffffu)));
        float eh2 = __half2float(__ushort_as_half((unsigned short)(r2.y >> 16)));
        float b0 = bf2f(hv2.x & 0xffffu), b1 = bf2f(hv2.x >> 16);
        float b2 = bf2f(hv2.y & 0xffffu), b3 = bf2f(hv2.y >> 16);
        float* zl2 = &z[dl2 * 129 + l16 * 4];
        atomicAdd(zl2 + 0,  el2 * b0);
        atomicAdd(zl2 + 1,  el2 * b1);
        atomicAdd(zl2 + 2,  el2 * b2);
        atomicAdd(zl2 + 3,  el2 * b3);
        atomicAdd(zl2 + 64, eh2 * b0);
        atomicAdd(zl2 + 65, eh2 * b1);
        atomicAdd(zl2 + 66, eh2 * b2);
        atomicAdd(zl2 + 67, eh2 * b3);
    }
    for (; k < end; k += 16) {
        uint2 r1 = ebuf[k];
        int s1 = r1.x & 0x1FFFF;
        uint2 hv1 = *(const uint2*)(hbf + (size_t)s1 * 64 + l16 * 4);
        int dl1 = (r1.x >> 17) & 31;
        float el1 = __half2float(__ushort_as_half((unsigned short)(r1.y & 0xffffu)));
        float eh1 = __half2float(__ushort_as_half((unsigned short)(r1.y >> 16)));
        float a0 = bf2f(hv1.x & 0xffffu), a1 = bf2f(hv1.x >> 16);
        float a2 = bf2f(hv1.y & 0xffffu), a3 = bf2f(hv1.y >> 16);
        float* zl1 = &z[dl1 * 129 + l16 * 4];
        atomicAdd(zl1 + 0,  el1 * a0);
        atomicAdd(zl1 + 1,  el1 * a1);
        atomicAdd(zl1 + 2,  el1 * a2);
        atomicAdd(zl1 + 3,  el1 * a3);
        atomicAdd(zl1 + 64, eh1 * a0);
        atomicAdd(zl1 + 65, eh1 * a1);
        atomicAdd(zl1 + 66, eh1 * a2);
        atomicAdd(zl1 + 67, eh1 * a3);
    }
    __syncthreads();

    // fused final transform: out[n] = z[n] . wrt + br
    int node = tid >> 3;          // 0..31
    int g = tid & 7;              // 8-col group
    float acc[8];
    #pragma unroll
    for (int j = 0; j < 8; ++j) acc[j] = 0.f;
    const float* zrow = z + node * 129;
    #pragma unroll 4
    for (int kk = 0; kk < 128; ++kk) {
        float zv = zrow[kk];                      // 8-lane same-addr broadcast
        const float* w = wrt + kk * 64 + g * 8;
        float4 w0 = *(const float4*)(w);
        float4 w1 = *(const float4*)(w + 4);
        acc[0] += zv * w0.x; acc[1] += zv * w0.y; acc[2] += zv * w0.z; acc[3] += zv * w0.w;
        acc[4] += zv * w1.x; acc[5] += zv * w1.y; acc[6] += zv * w1.z; acc[7] += zv * w1.w;
    }
    int n = bk * NPB + node;
    float* op = out + (size_t)n * 64 + g * 8;
    const float* bp = br + g * 8;
    *(float4*)(op)     = make_float4(acc[0] + bp[0], acc[1] + bp[1], acc[2] + bp[2], acc[3] + bp[3]);
    *(float4*)(op + 4) = make_float4(acc[4] + bp[4], acc[5] + bp[5], acc[6] + bp[6], acc[7] + bp[7]);
}

// ---------------------------------------------------------------------------
extern "C" void kernel_launch(void* const* d_in, const int* in_sizes, int n_in,
                              void* d_out, int out_size, void* d_ws, size_t ws_size,
                              hipStream_t stream) {
    const float* h    = (const float*)d_in[0];
    const float* dvec = (const float*)d_in[1];
    const int*   src  = (const int*)  d_in[2];
    const int*   dst  = (const int*)  d_in[3];
    const float* Wl   = (const float*)d_in[4];
    const float* bl   = (const float*)d_in[5];
    const float* Wh   = (const float*)d_in[6];
    const float* bh   = (const float*)d_in[7];
    const float* Wr   = (const float*)d_in[8];
    const float* br   = (const float*)d_in[9];
    float* out = (float*)d_out;

    char* ws = (char*)d_ws;
    size_t off = 0;
    auto alloc = [&](size_t bytes) { char* p = ws + off; off += (bytes + 255) & ~size_t(255); return p; };

    ushort_t* hbf       = (ushort_t*)alloc((size_t)N_NODES * 64 * 2);     // 12.8 MB
    float4*   gdst4     = (float4*)  alloc((size_t)N_NODES * 16);         // 1.6 MB
    float4*   gsrc4     = (float4*)  alloc((size_t)N_NODES * 16);         // 1.6 MB
    float*    wrt       = (float*)   alloc(64 * 128 * 4);                 // 32 KB
    int*      T         = (int*)     alloc((size_t)NT * NB * 4);          // 2.45 MB
    int*      totG      = (int*)     alloc((size_t)NB * 4);
    int*      baseG     = (int*)     alloc((size_t)NB * 4);
    int*      bucketoffs= (int*)     alloc((size_t)(NB + 1) * 4);
    uint2*    ebuf      = (uint2*)   alloc((size_t)N_EDGES * 8);          // 12.8 MB

    transpose_wr_kernel<<<1, 256, 0, stream>>>(Wr, wrt);
    node_gates_kernel<<<(N_NODES + 3) / 4, 256, 0, stream>>>(h, dvec, Wl, Wh, hbf, gdst4, gsrc4);
    bucket_hist_kernel<<<NT, 1024, 0, stream>>>(dst, T);
    scanA_kernel<<<(NB + 1023) / 1024, 1024, 0, stream>>>(T, totG);
    scanB_kernel<<<1, 1024, 0, stream>>>(totG, baseG, bucketoffs);
    place_kernel<<<NT, 1024, 0, stream>>>(src, dst, T, baseG, gdst4, gsrc4, bl, bh, ebuf);
    accum_final_kernel<<<NB, 256, 0, stream>>>(bucketoffs, ebuf, hbf, wrt, br, out);
}

// Round 6
// 329.522 us; speedup vs baseline: 4.0049x; 3.9479x over previous
//
#include <hip/hip_runtime.h>
#include <hip/hip_fp16.h>
#include <math.h>

#define N_NODES 100000
#define D_DIM   64
#define N_EDGES 1600000
#define P_L 0.5f
#define P_H 0.5f

#define NPB   32                       // nodes per bucket (exact: 32*3125=100000)
#define NB    3125                     // number of buckets
#define TILE  8192                     // edges per partition tile
#define NT    ((N_EDGES + TILE - 1) / TILE)   // 196 tiles
#define CAP   1024                     // per-bucket record capacity (mean 512, +22 sigma)
#define ZS    132                      // z row stride (16B-aligned rows, bank-spread)

typedef unsigned int uint;
typedef unsigned short ushort_t;

__device__ inline ushort_t f2bf(float f) {
    uint u = __float_as_uint(f);
    uint r = (u + 0x7fffu + ((u >> 16) & 1u)) >> 16;
    return (ushort_t)r;
}
__device__ inline float bf2f(uint u) { return __uint_as_float(u << 16); }

// fast tanh for x >= 0
__device__ inline float tanh_pos(float x) {
    return 1.f - 2.f / (__expf(2.f * x) + 1.f);
}

// ---------------------------------------------------------------------------
// K0: transpose Wr [64c][128k] -> wrt [128k][64c]
// ---------------------------------------------------------------------------
__global__ __launch_bounds__(256) void transpose_wr_kernel(const float* __restrict__ Wr,
                                                           float* __restrict__ wrt) {
    for (int idx = threadIdx.x; idx < 64 * 128; idx += 256) {
        int c = idx >> 7;
        int k = idx & 127;
        wrt[k * 64 + c] = Wr[idx];
    }
}

// ---------------------------------------------------------------------------
// K1: per-node gate projections + h -> bf16. One wave per node.
// ---------------------------------------------------------------------------
__global__ __launch_bounds__(256) void node_gates_kernel(
    const float* __restrict__ h, const float* __restrict__ dvec,
    const float* __restrict__ Wl, const float* __restrict__ Wh,
    ushort_t* __restrict__ hbf,
    float4* __restrict__ gdst4, float4* __restrict__ gsrc4)
{
    int tid = threadIdx.x;
    int node = blockIdx.x * 4 + (tid >> 6);
    if (node >= N_NODES) return;
    int lane = tid & 63;

    float hv = h[(size_t)node * 64 + lane];
    hbf[(size_t)node * 64 + lane] = f2bf(hv);

    float pld = hv * Wl[lane];
    float pls = hv * Wl[64 + lane];
    float phd = hv * Wh[lane];
    float phs = hv * Wh[64 + lane];
    #pragma unroll
    for (int m = 32; m >= 1; m >>= 1) {
        pld += __shfl_xor(pld, m);
        pls += __shfl_xor(pls, m);
        phd += __shfl_xor(phd, m);
        phs += __shfl_xor(phs, m);
    }
    if (lane == 0) {
        float d = dvec[node];
        gdst4[node] = make_float4(pld, phd, d, 0.f);
        gsrc4[node] = make_float4(pls, phs, d, 0.f);
    }
}

// ---------------------------------------------------------------------------
// K2: per-tile bucket histogram (int LDS atomics) -> T[tile][bucket]
// ---------------------------------------------------------------------------
__global__ __launch_bounds__(1024) void bucket_hist_kernel(const int* __restrict__ dst,
                                                           int* __restrict__ T) {
    __shared__ int hist[NB];
    int tid = threadIdx.x;
    for (int i = tid; i < NB; i += 1024) hist[i] = 0;
    __syncthreads();
    int base = blockIdx.x * TILE;
    #pragma unroll
    for (int j = 0; j < TILE / 1024; ++j) {
        int e = base + j * 1024 + tid;
        if (e < N_EDGES) atomicAdd(&hist[dst[e] >> 5], 1);
    }
    __syncthreads();
    int* row = T + (size_t)blockIdx.x * NB;
    for (int i = tid; i < NB; i += 1024) row[i] = hist[i];
}

// ---------------------------------------------------------------------------
// K3a: column scan of T over tiles; totG[b] = column total.
// ---------------------------------------------------------------------------
__global__ __launch_bounds__(1024) void scanA_kernel(int* __restrict__ T,
                                                     int* __restrict__ totG) {
    int b = blockIdx.x * 1024 + threadIdx.x;
    if (b >= NB) return;
    int run = 0;
    for (int w = 0; w < NT; ++w) {
        int idx = w * NB + b;
        int v = T[idx];
        T[idx] = run;
        run += v;
    }
    totG[b] = run;
}

// ---------------------------------------------------------------------------
// K3b: exclusive scan of totG[NB] -> baseG, bucketoffs. One block.
// ---------------------------------------------------------------------------
__global__ __launch_bounds__(1024) void scanB_kernel(const int* __restrict__ totG,
                                                     int* __restrict__ baseG,
                                                     int* __restrict__ bucketoffs) {
    __shared__ int scan_lds[1024];
    int tid = threadIdx.x;
    int a[4];
    int s = 0;
    #pragma unroll
    for (int i = 0; i < 4; ++i) {
        int b = tid * 4 + i;
        a[i] = (b < NB) ? totG[b] : 0;
        s += a[i];
    }
    scan_lds[tid] = s;
    __syncthreads();
    for (int d = 1; d < 1024; d <<= 1) {
        int v = (tid >= d) ? scan_lds[tid - d] : 0;
        __syncthreads();
        scan_lds[tid] += v;
        __syncthreads();
    }
    int excl = scan_lds[tid] - s;
    int total = scan_lds[1023];
    #pragma unroll
    for (int i = 0; i < 4; ++i) {
        int b = tid * 4 + i;
        if (b < NB) { baseG[b] = excl; bucketoffs[b] = excl; }
        excl += a[i];
    }
    if (tid == 0) bucketoffs[NB] = total;
}

// ---------------------------------------------------------------------------
// K4: place edges into bucket-partitioned ebuf. LDS int cursors only.
// Record: (src | dstLocal<<17, half el | half eh << 16).
// ---------------------------------------------------------------------------
__global__ __launch_bounds__(1024) void place_kernel(
    const int* __restrict__ src, const int* __restrict__ dst,
    const int* __restrict__ T, const int* __restrict__ baseG,
    const float4* __restrict__ gdst4, const float4* __restrict__ gsrc4,
    const float* __restrict__ bl, const float* __restrict__ bh,
    uint2* __restrict__ ebuf)
{
    __shared__ int cur[NB];
    int tid = threadIdx.x;
    const int* row = T + (size_t)blockIdx.x * NB;
    for (int i = tid; i < NB; i += 1024) cur[i] = row[i] + baseG[i];
    __syncthreads();

    float bl0 = bl[0], bh0 = bh[0];
    int base = blockIdx.x * TILE;
    #pragma unroll
    for (int j = 0; j < TILE / 1024; ++j) {
        int e = base + j * 1024 + tid;
        if (e >= N_EDGES) continue;
        int t = dst[e];
        int s = src[e];
        float4 gt = gdst4[t];
        float4 gs = gsrc4[s];
        float xl = gt.x + gs.x + bl0;
        float xh = gt.y + gs.y + bh0;
        float ll = xl > 0.f ? xl : -P_L * xl;   // leaky, always >= 0
        float hh = xh > 0.f ? xh : -P_H * xh;
        float dd = gt.z * gs.z;
        float el =  tanh_pos(ll) * dd;
        float eh = -tanh_pos(hh) * dd;
        uint ge = (uint)__half_as_ushort(__float2half_rn(el))
                | ((uint)__half_as_ushort(__float2half_rn(eh)) << 16);
        int b  = t >> 5;
        uint dl = (uint)(t & 31);
        int pos = atomicAdd(&cur[b], 1);        // int LDS atomic
        ebuf[pos] = make_uint2((uint)s | (dl << 17), ge);
    }
}

// ---------------------------------------------------------------------------
// K5: per-bucket accumulate + fused Wr transform. ZERO fp32 atomics.
// Phase 1: int-LDS histogram of the bucket's records by dst-local id.
// Phase 2: 32-lane shfl scan -> per-node base offsets.
// Phase 3: counting-sort scatter of records into LDS (int cursor atomics).
// Phase 4: one 16-lane subgroup per node, VGPR accumulation, plain z write.
// Phase 5: fused out = z . wrt + br.
// ---------------------------------------------------------------------------
__global__ __launch_bounds__(256) void accum_final_kernel(
    const int* __restrict__ bucketoffs, const uint2* __restrict__ ebuf,
    const ushort_t* __restrict__ hbf, const float* __restrict__ wrt,
    const float* __restrict__ br, float* __restrict__ out)
{
    __shared__ float z[NPB * ZS];
    __shared__ uint2 srec[CAP];
    __shared__ int ncount[NPB];
    __shared__ int nbase[NPB];
    __shared__ int ncur[NPB];

    int tid = threadIdx.x;
    int bk = blockIdx.x;
    int beg = bucketoffs[bk];
    int end = bucketoffs[bk + 1];
    int cnt = end - beg;
    if (cnt > CAP) cnt = CAP;    // statistically impossible (mean 512, +22 sigma)

    if (tid < NPB) ncount[tid] = 0;
    __syncthreads();

    // phase 1: histogram by dst-local
    for (int i = tid; i < cnt; i += 256) {
        uint2 r = ebuf[beg + i];
        atomicAdd(&ncount[(r.x >> 17) & 31], 1);
    }
    __syncthreads();

    // phase 2: exclusive scan of 32 counts (lanes 0..31 of wave 0)
    if (tid < 32) {
        int v = ncount[tid];
        int p = v;
        #pragma unroll
        for (int d = 1; d < 32; d <<= 1) {
            int x = __shfl_up(p, d);
            if (tid >= d) p += x;
        }
        nbase[tid] = p - v;
        ncur[tid]  = p - v;
    }
    __syncthreads();

    // phase 3: counting-sort scatter into LDS
    for (int i = tid; i < cnt; i += 256) {
        uint2 r = ebuf[beg + i];
        int dl = (r.x >> 17) & 31;
        int slot = atomicAdd(&ncur[dl], 1);
        srec[slot] = r;
    }
    __syncthreads();

    // phase 4: subgroup sg owns nodes sg and sg+16; VGPR accumulation
    int sg  = tid >> 4;
    int l16 = tid & 15;
    #pragma unroll
    for (int half = 0; half < 2; ++half) {
        int dl = sg + half * 16;
        int rbeg = nbase[dl];
        int rend = ncur[dl];          // == rbeg + count after phase 3

        float acc[8];
        #pragma unroll
        for (int j = 0; j < 8; ++j) acc[j] = 0.f;

        int k = rbeg;
        for (; k + 1 < rend; k += 2) {
            uint2 r1 = srec[k];       // same addr across 16 lanes: LDS broadcast
            uint2 r2 = srec[k + 1];
            int s1 = r1.x & 0x1FFFF;
            int s2 = r2.x & 0x1FFFF;
            uint2 hv1 = *(const uint2*)(hbf + (size_t)s1 * 64 + l16 * 4);
            uint2 hv2 = *(const uint2*)(hbf + (size_t)s2 * 64 + l16 * 4);

            float el1 = __half2float(__ushort_as_half((unsigned short)(r1.y & 0xffffu)));
            float eh1 = __half2float(__ushort_as_half((unsigned short)(r1.y >> 16)));
            float a0 = bf2f(hv1.x & 0xffffu), a1 = bf2f(hv1.x >> 16);
            float a2 = bf2f(hv1.y & 0xffffu), a3 = bf2f(hv1.y >> 16);
            acc[0] += el1 * a0; acc[1] += el1 * a1; acc[2] += el1 * a2; acc[3] += el1 * a3;
            acc[4] += eh1 * a0; acc[5] += eh1 * a1; acc[6] += eh1 * a2; acc[7] += eh1 * a3;

            float el2 = __half2float(__ushort_as_half((unsigned short)(r2.y & 0xffffu)));
            float eh2 = __half2float(__ushort_as_half((unsigned short)(r2.y >> 16)));
            float b0 = bf2f(hv2.x & 0xffffu), b1 = bf2f(hv2.x >> 16);
            float b2 = bf2f(hv2.y & 0xffffu), b3 = bf2f(hv2.y >> 16);
            acc[0] += el2 * b0; acc[1] += el2 * b1; acc[2] += el2 * b2; acc[3] += el2 * b3;
            acc[4] += eh2 * b0; acc[5] += eh2 * b1; acc[6] += eh2 * b2; acc[7] += eh2 * b3;
        }
        if (k < rend) {
            uint2 r1 = srec[k];
            int s1 = r1.x & 0x1FFFF;
            uint2 hv1 = *(const uint2*)(hbf + (size_t)s1 * 64 + l16 * 4);
            float el1 = __half2float(__ushort_as_half((unsigned short)(r1.y & 0xffffu)));
            float eh1 = __half2float(__ushort_as_half((unsigned short)(r1.y >> 16)));
            float a0 = bf2f(hv1.x & 0xffffu), a1 = bf2f(hv1.x >> 16);
            float a2 = bf2f(hv1.y & 0xffffu), a3 = bf2f(hv1.y >> 16);
            acc[0] += el1 * a0; acc[1] += el1 * a1; acc[2] += el1 * a2; acc[3] += el1 * a3;
            acc[4] += eh1 * a0; acc[5] += eh1 * a1; acc[6] += eh1 * a2; acc[7] += eh1 * a3;
        }

        // plain (non-atomic) z writes: each (node, element) owned by one lane
        float* zp = &z[dl * ZS + l16 * 4];
        zp[0] = acc[0]; zp[1] = acc[1]; zp[2] = acc[2]; zp[3] = acc[3];
        zp[64] = acc[4]; zp[65] = acc[5]; zp[66] = acc[6]; zp[67] = acc[7];
    }
    __syncthreads();

    // phase 5: fused final transform out[n] = z[n] . wrt + br
    int node = tid >> 3;          // 0..31
    int g = tid & 7;              // 8-col group
    float acc[8];
    #pragma unroll
    for (int j = 0; j < 8; ++j) acc[j] = 0.f;
    const float* zrow = z + node * ZS;
    #pragma unroll 4
    for (int kk = 0; kk < 128; ++kk) {
        float zv = zrow[kk];                      // 8-lane same-addr broadcast
        const float* w = wrt + kk * 64 + g * 8;
        float4 w0 = *(const float4*)(w);
        float4 w1 = *(const float4*)(w + 4);
        acc[0] += zv * w0.x; acc[1] += zv * w0.y; acc[2] += zv * w0.z; acc[3] += zv * w0.w;
        acc[4] += zv * w1.x; acc[5] += zv * w1.y; acc[6] += zv * w1.z; acc[7] += zv * w1.w;
    }
    int n = bk * NPB + node;
    float* op = out + (size_t)n * 64 + g * 8;
    const float* bp = br + g * 8;
    *(float4*)(op)     = make_float4(acc[0] + bp[0], acc[1] + bp[1], acc[2] + bp[2], acc[3] + bp[3]);
    *(float4*)(op + 4) = make_float4(acc[4] + bp[4], acc[5] + bp[5], acc[6] + bp[6], acc[7] + bp[7]);
}

// ---------------------------------------------------------------------------
extern "C" void kernel_launch(void* const* d_in, const int* in_sizes, int n_in,
                              void* d_out, int out_size, void* d_ws, size_t ws_size,
                              hipStream_t stream) {
    const float* h    = (const float*)d_in[0];
    const float* dvec = (const float*)d_in[1];
    const int*   src  = (const int*)  d_in[2];
    const int*   dst  = (const int*)  d_in[3];
    const float* Wl   = (const float*)d_in[4];
    const float* bl   = (const float*)d_in[5];
    const float* Wh   = (const float*)d_in[6];
    const float* bh   = (const float*)d_in[7];
    const float* Wr   = (const float*)d_in[8];
    const float* br   = (const float*)d_in[9];
    float* out = (float*)d_out;

    char* ws = (char*)d_ws;
    size_t off = 0;
    auto alloc = [&](size_t bytes) { char* p = ws + off; off += (bytes + 255) & ~size_t(255); return p; };

    ushort_t* hbf       = (ushort_t*)alloc((size_t)N_NODES * 64 * 2);     // 12.8 MB
    float4*   gdst4     = (float4*)  alloc((size_t)N_NODES * 16);         // 1.6 MB
    float4*   gsrc4     = (float4*)  alloc((size_t)N_NODES * 16);         // 1.6 MB
    float*    wrt       = (float*)   alloc(64 * 128 * 4);                 // 32 KB
    int*      T         = (int*)     alloc((size_t)NT * NB * 4);          // 2.45 MB
    int*      totG      = (int*)     alloc((size_t)NB * 4);
    int*      baseG     = (int*)     alloc((size_t)NB * 4);
    int*      bucketoffs= (int*)     alloc((size_t)(NB + 1) * 4);
    uint2*    ebuf      = (uint2*)   alloc((size_t)N_EDGES * 8);          // 12.8 MB

    transpose_wr_kernel<<<1, 256, 0, stream>>>(Wr, wrt);
    node_gates_kernel<<<(N_NODES + 3) / 4, 256, 0, stream>>>(h, dvec, Wl, Wh, hbf, gdst4, gsrc4);
    bucket_hist_kernel<<<NT, 1024, 0, stream>>>(dst, T);
    scanA_kernel<<<(NB + 1023) / 1024, 1024, 0, stream>>>(T, totG);
    scanB_kernel<<<1, 1024, 0, stream>>>(totG, baseG, bucketoffs);
    place_kernel<<<NT, 1024, 0, stream>>>(src, dst, T, baseG, gdst4, gsrc4, bl, bh, ebuf);
    accum_final_kernel<<<NB, 256, 0, stream>>>(bucketoffs, ebuf, hbf, wrt, br, out);
}